// Round 5
// baseline (627.898 us; speedup 1.0000x reference)
//
#include <hip/hip_runtime.h>
#include <math.h>

// Problem constants (B=8, Cin=Cout=64, H=W=64, 3x3 kernel pad 1)
#define NB     8
#define NC     64
#define HW     4096           // 64*64
#define PLANE  2097152        // NB*NC*HW

// Workspace layout (float-slot offsets)
#define WS_WB     0           // bf16 wB[8][72][64][8]   (294912 bf16 = 147456 f)
#define WS_OWB    147456      // bf16 owB[8][72][32][8]  (147456 bf16 = 73728 f)
#define WS_OB     221184      // f32 obAll[8][27]
#define WS_GATES  221400      // f32 gates_scr[4][8][64][4096] = 8388608 (D-scrambled)
#define WS_XT     8610008     // bf16 xT[8][4096][64] HWC  (1048576 f)
#define WS_HT     9658584     // bf16 hT[8][4096][64] HWC  (1048576 f)
// total = 10707160 floats = 42.8 MB

typedef __bf16 bf16x8 __attribute__((ext_vector_type(8)));
typedef float  f32x4  __attribute__((ext_vector_type(4)));

struct Params {
    const float* x; const float* h; const float* c;
    const float* w[8]; const float* ow[8]; const float* ob[8];
    const float* bi; const float* bf; const float* bc; const float* bo;
    const float* wci; const float* wcf; const float* wco;
    float* out; float* ws;
};

__device__ __forceinline__ float sigf(float v) { return 1.f / (1.f + __expf(-v)); }
__device__ __forceinline__ unsigned short f2bf(float v) {
    __bf16 b = (__bf16)v;
    return __builtin_bit_cast(unsigned short, b);
}
// bf16 pair unpack: lo/hi halves of a dword -> f32 (1 inst each)
__device__ __forceinline__ float blo(unsigned d) { return __builtin_bit_cast(float, d << 16); }
__device__ __forceinline__ float bhi(unsigned d) { return __builtin_bit_cast(float, d & 0xffff0000u); }

// ---------------------------------------------------------------------------
// K0: pack weights into MFMA B-fragment layouts (bf16) + biases.
//   Tap-major K-order: k = ktap*64 + c.
//   wB [br][kgrp][o(64)][j],  owB[br][kgrp][o(32)][j] (o>=27 zero-padded)
// ---------------------------------------------------------------------------
__global__ __launch_bounds__(256) void k0_prep(Params p) {
    int i = blockIdx.x * 256 + threadIdx.x;
    unsigned short* wb  = (unsigned short*)(p.ws + WS_WB);
    unsigned short* owb = (unsigned short*)(p.ws + WS_OWB);
    if (i < 294912) {
        int br = i / 36864; int r = i % 36864;
        int kgrp = r >> 9; int o = (r >> 3) & 63; int j = r & 7;
        int k = kgrp * 8 + j;
        int ktap = k >> 6; int c = k & 63;
        wb[i] = f2bf(p.w[br][(o * 64 + c) * 9 + ktap]);
    } else if (i < 294912 + 147456) {
        int ii = i - 294912;
        int br = ii / 18432; int r = ii % 18432;
        int kgrp = r >> 8; int o = (r >> 3) & 31; int j = r & 7;
        int k = kgrp * 8 + j;
        int ktap = k >> 6; int c = k & 63;
        float v = (o < 27) ? p.ow[br][(o * 64 + c) * 9 + ktap] : 0.f;
        owb[ii] = f2bf(v);
    } else if (i < 294912 + 147456 + 216) {
        int ii = i - 442368;
        int br = ii / 27; int j = ii % 27;
        p.ws[WS_OB + ii] = p.ob[br][j];
    }
}

// ---------------------------------------------------------------------------
// K0T: CHW fp32 -> HWC bf16 transpose of x and h.
// ---------------------------------------------------------------------------
__global__ __launch_bounds__(256) void k0_transp(Params p) {
    __shared__ float tile[64][65];
    int bid = blockIdx.x;
    int row = bid & 63; int b = (bid >> 6) & 7; int ten = bid >> 9;
    const float* src = ten ? p.h : p.x;
    unsigned short* dst = (unsigned short*)(p.ws + (ten ? WS_HT : WS_XT));
    int t = threadIdx.x; int lane = t & 63; int w4 = t >> 6;
#pragma unroll
    for (int i = 0; i < 16; ++i) {
        int c = i * 4 + w4;
        tile[c][lane] = src[((size_t)(b * 64 + c) << 12) + row * 64 + lane];
    }
    __syncthreads();
#pragma unroll
    for (int i = 0; i < 16; ++i) {
        int px = i * 4 + w4;
        dst[((size_t)(b * 4096 + row * 64 + px) << 6) + lane] = f2bf(tile[lane][px]);
    }
}

// ---------------------------------------------------------------------------
// K2 v5 (fused): offset-conv (ex-K1) + deform gather + MFMA reduce, one pass.
//   grid: gate(4) * row(64) * b(8) = 2048 blocks of 256. Wave = px-tile.
//   Per sub: (1) offset conv via MFMA, D-frags + bias -> sOff LDS;
//   (2) Phase A: bilinear coords from sOff -> sA/sW; (3) gather directly
//   into A-frags (4 corner uint4 loads per K-step) + MFMA.
//   Epilogue: D-scrambled coalesced float4 store (K3 decodes).
//   LDS arena 22272 B: rb(8448) aliases sA(4608)+sW(9216); sOff(8448) after.
// ---------------------------------------------------------------------------
__global__ __launch_bounds__(256, 6) void k2_fused(Params p) {
    __shared__ __align__(16) unsigned char arena[22272];
    unsigned short* rb = (unsigned short*)arena;            // [cg][px+2][8] bf16
    uint2*  sA   = (uint2*)arena;                           // [9][64]
    float4* sWp  = (float4*)(arena + 4608);                 // [9][64]
    float*  sOff = (float*)(arena + 13824);                 // [32][66]

    int bid = blockIdx.x;
    int gate = bid & 3; int row = (bid >> 2) & 63; int b = bid >> 8;
    int t = threadIdx.x; int l = t & 63; int w = t >> 6;
    int q = l >> 4; int n = l & 15;
    int pxl = w * 16 + n;

    const unsigned short* wBp = (const unsigned short*)(p.ws + WS_WB);
    const unsigned short* owb = (const unsigned short*)(p.ws + WS_OWB);

    f32x4 acc[4];
#pragma unroll
    for (int ot = 0; ot < 4; ++ot) acc[ot] = (f32x4){0.f, 0.f, 0.f, 0.f};

    for (int sub = 0; sub < 2; ++sub) {
        int br = gate * 2 + sub;
        const unsigned short* inT =
            (const unsigned short*)(p.ws + (sub ? WS_HT : WS_XT)) + ((size_t)b << 18);
        const float* obp = p.ws + WS_OB + br * 27;

        // ---- fused offset conv: M=16 px (this wave's tile), N=32, K=576 ----
        f32x4 acc2[2];
        acc2[0] = (f32x4){0.f, 0.f, 0.f, 0.f};
        acc2[1] = (f32x4){0.f, 0.f, 0.f, 0.f};
        for (int dy = 0; dy < 3; ++dy) {
            int srow = row + dy - 1;
            __syncthreads();          // rb region free (prev phase/iter done)
#pragma unroll
            for (int ii = 0; ii < 3; ++ii) {
                int unit = t + ii * 256;
                if (unit < 528) {
                    int pxi = unit >> 3; int cg = unit & 7; int spx = pxi - 1;
                    uint4 v = {0u, 0u, 0u, 0u};
                    if (((unsigned)srow < 64u) && ((unsigned)spx < 64u))
                        v = *(const uint4*)(inT + (((size_t)srow * 64 + spx) << 6) + cg * 8);
                    *(uint4*)(rb + (cg * 66 + pxi) * 8) = v;
                }
            }
            __syncthreads();
#pragma unroll
            for (int s = 0; s < 6; ++s) {
                int dxk = s >> 1; int cgb = (s & 1) * 4 + q;
                bf16x8 af = *(const bf16x8*)(rb + (cgb * 66 + w * 16 + n + dxk) * 8);
                int kb = (br * 72 + dy * 24 + s * 4 + q) * 32;
#pragma unroll
                for (int ot = 0; ot < 2; ++ot) {
                    bf16x8 bfg = *(const bf16x8*)(owb + (size_t)(kb + ot * 16 + n) * 8);
                    acc2[ot] = __builtin_amdgcn_mfma_f32_16x16x32_bf16(af, bfg, acc2[ot], 0, 0, 0);
                }
            }
        }
        // D-frags (+bias) -> sOff[j][px]; j=ot*16+n, px=w*16+q*4+r
#pragma unroll
        for (int ot = 0; ot < 2; ++ot) {
            int j = ot * 16 + n;
            float bias = (j < 27) ? obp[j] : 0.f;
#pragma unroll
            for (int r = 0; r < 4; ++r)
                sOff[j * 66 + w * 16 + q * 4 + r] = acc2[ot][r] + bias;
        }
        __syncthreads();   // sOff visible; rb dead -> sA/sW writable

        // ---- Phase A: bilinear coords + (mask*inbound)-folded weights ----
        for (int i2 = t; i2 < 576; i2 += 256) {
            int px = i2 & 63; int k = i2 >> 6;
            float dy = sOff[(2 * k) * 66 + px];
            float dx = sOff[(2 * k + 1) * 66 + px];
            float mm = sOff[(18 + k) * 66 + px];
            float m = sigf(mm);
            int ki = k / 3, kj = k % 3;
            float py  = (float)(row + ki - 1) + dy;
            float pxx = (float)(px + kj - 1) + dx;
            float y0f = floorf(py), x0f = floorf(pxx);
            float wy = py - y0f, wx = pxx - x0f;
            int y0 = (int)y0f, x0 = (int)x0f;
            float y0i = ((unsigned)y0 < 64u) ? 1.f : 0.f;
            float y1i = ((unsigned)(y0 + 1) < 64u) ? 1.f : 0.f;
            float x0i = ((unsigned)x0 < 64u) ? 1.f : 0.f;
            float x1i = ((unsigned)(x0 + 1) < 64u) ? 1.f : 0.f;
            float w00 = (1.f - wy) * (1.f - wx) * m * y0i * x0i;
            float w01 = (1.f - wy) * wx         * m * y0i * x1i;
            float w10 = wy         * (1.f - wx) * m * y1i * x0i;
            float w11 = wy         * wx         * m * y1i * x1i;
            int cy0 = min(max(y0, 0), 63),     cy1 = min(max(y0 + 1, 0), 63);
            int cx0 = min(max(x0, 0), 63),     cx1 = min(max(x0 + 1, 0), 63);
            sA[k * 64 + px] = make_uint2((unsigned)(cy0 * 64 + cx0) | ((unsigned)(cy0 * 64 + cx1) << 16),
                                         (unsigned)(cy1 * 64 + cx0) | ((unsigned)(cy1 * 64 + cx1) << 16));
            sWp[k * 64 + px] = make_float4(w00, w01, w10, w11);
        }
        __syncthreads();

        // ---- gather directly into A-frags + main MFMA ----
        const unsigned short* cbase = inT + q * 8;
        for (int ktap = 0; ktap < 9; ++ktap) {
            uint2 aa = sA[ktap * 64 + pxl];
            float4 wv = sWp[ktap * 64 + pxl];
            unsigned i0 = (aa.x & 0xffffu) << 6;
            unsigned i1 = (aa.x >> 16) << 6;
            unsigned i2 = (aa.y & 0xffffu) << 6;
            unsigned i3 = (aa.y >> 16) << 6;
#pragma unroll
            for (int half = 0; half < 2; ++half) {
                int s = ktap * 2 + half;
                const unsigned short* cb = cbase + half * 32;
                uint4 A0 = *(const uint4*)(cb + i0);
                uint4 A1 = *(const uint4*)(cb + i1);
                uint4 A2 = *(const uint4*)(cb + i2);
                uint4 A3 = *(const uint4*)(cb + i3);
                bf16x8 af;
#define COMB(m, d0, d1, d2, d3)                                                   \
                af[2*m]   = (__bf16)(wv.x*blo(d0) + wv.y*blo(d1) + wv.z*blo(d2) + wv.w*blo(d3)); \
                af[2*m+1] = (__bf16)(wv.x*bhi(d0) + wv.y*bhi(d1) + wv.z*bhi(d2) + wv.w*bhi(d3));
                COMB(0, A0.x, A1.x, A2.x, A3.x)
                COMB(1, A0.y, A1.y, A2.y, A3.y)
                COMB(2, A0.z, A1.z, A2.z, A3.z)
                COMB(3, A0.w, A1.w, A2.w, A3.w)
#undef COMB
                int kb = (br * 72 + s * 4 + q) * 64;
#pragma unroll
                for (int ot = 0; ot < 4; ++ot) {
                    bf16x8 bfg = *(const bf16x8*)(wBp + (size_t)(kb + ot * 16 + n) * 8);
                    acc[ot] = __builtin_amdgcn_mfma_f32_16x16x32_bf16(af, bfg, acc[ot], 0, 0, 0);
                }
            }
        }
        __syncthreads();   // protect sA/sW/arena before next sub's rb staging
    }

    // epilogue: direct D-scrambled coalesced store; K3 decodes.
    float* gp = p.ws + WS_GATES + ((size_t)((gate * 8 + b) * 64 + row) << 12);
#pragma unroll
    for (int ot = 0; ot < 4; ++ot)
        *(float4*)(gp + ((w * 4 + ot) * 64 + l) * 4) = *(float4*)&acc[ot];
}

// ---------------------------------------------------------------------------
// K3: pointwise ConvLSTM combine, reading D-scrambled gates (coalesced) and
//   decoding (o,px) for c/out access (16B-segment granularity).
//   grid: 8192 blocks of 256.
// ---------------------------------------------------------------------------
__global__ __launch_bounds__(256) void k3_lstm(Params p) {
    int T = blockIdx.x * 256 + threadIdx.x;        // [b][row][i] over scrambled
    int i = T & 4095; int row = (T >> 12) & 63; int b = T >> 18;
    const float* gp = p.ws + WS_GATES;
    size_t base = ((size_t)(b * 64 + row) << 12) + i;
    float gi = gp[base];
    float gf = gp[base + 1 * PLANE];
    float gc = gp[base + 2 * PLANE];
    float go = gp[base + 3 * PLANE];
    // decode scramble: i = ((w*4+ot)*64 + l)*4 + r
    int r = i & 3; int l = (i >> 2) & 63; int u = i >> 8;
    int w = u >> 2; int ot = u & 3;
    int o = ot * 16 + (l & 15);
    int px = w * 16 + (l >> 4) * 4 + r;
    size_t cidx = ((size_t)(b * 64 + o) << 12) + row * 64 + px;
    float cold = p.c[cidx];
    float ig = sigf(gi + cold * p.wci[o] + p.bi[o]);
    float fg = sigf(gf + cold * p.wcf[o] + p.bf[o]);
    float cn = fg * cold + ig * tanhf(gc + p.bc[o]);
    float og = sigf(go + cn * p.wco[o] + p.bo[o]);
    p.out[cidx] = og * tanhf(cn);
    p.out[cidx + PLANE] = cn;
}

// ---------------------------------------------------------------------------
extern "C" void kernel_launch(void* const* d_in, const int* in_sizes, int n_in,
                              void* d_out, int out_size, void* d_ws, size_t ws_size,
                              hipStream_t stream) {
    (void)in_sizes; (void)n_in; (void)out_size; (void)ws_size;
    Params P;
    P.x = (const float*)d_in[0];
    P.h = (const float*)d_in[1];
    P.c = (const float*)d_in[2];
    for (int i = 0; i < 8; ++i) {
        P.w[i]  = (const float*)d_in[3 + 3 * i];
        P.ow[i] = (const float*)d_in[4 + 3 * i];
        P.ob[i] = (const float*)d_in[5 + 3 * i];
    }
    P.bi  = (const float*)d_in[27];
    P.bf  = (const float*)d_in[28];
    P.bc  = (const float*)d_in[29];
    P.bo  = (const float*)d_in[30];
    P.wci = (const float*)d_in[31];
    P.wcf = (const float*)d_in[32];
    P.wco = (const float*)d_in[33];
    P.out = (float*)d_out;
    P.ws  = (float*)d_ws;

    k0_prep   <<<dim3(1729), dim3(256), 0, stream>>>(P);
    k0_transp <<<dim3(1024), dim3(256), 0, stream>>>(P);
    k2_fused  <<<dim3(2048), dim3(256), 0, stream>>>(P);
    k3_lstm   <<<dim3(8192), dim3(256), 0, stream>>>(P);
}

// Round 6
// 384.289 us; speedup vs baseline: 1.6339x; 1.6339x over previous
//
#include <hip/hip_runtime.h>
#include <math.h>

// Problem constants (B=8, Cin=Cout=64, H=W=64, 3x3 kernel pad 1)
#define NB     8
#define NC     64
#define HW     4096           // 64*64
#define PLANE  2097152        // NB*NC*HW

// Workspace layout (float-slot offsets)
#define WS_WB     0           // bf16 wB[8][72][64][8]   (294912 bf16 = 147456 f)
#define WS_OWB    147456      // bf16 owB[8][72][32][8]  (147456 bf16 = 73728 f)
#define WS_OB     221184      // f32 obAll[8][27]
#define WS_GATES  221400      // f32 gates_scr[4][8][64][4096] = 8388608 (D-scrambled)
#define WS_XT     8610008     // bf16 xT[8][4096][64] HWC  (1048576 f)
#define WS_HT     9658584     // bf16 hT[8][4096][64] HWC  (1048576 f)
// total = 10707160 floats = 42.8 MB

typedef __bf16 bf16x8 __attribute__((ext_vector_type(8)));
typedef float  f32x4  __attribute__((ext_vector_type(4)));

struct Params {
    const float* x; const float* h; const float* c;
    const float* w[8]; const float* ow[8]; const float* ob[8];
    const float* bi; const float* bf; const float* bc; const float* bo;
    const float* wci; const float* wcf; const float* wco;
    float* out; float* ws;
};

__device__ __forceinline__ float sigf(float v) { return 1.f / (1.f + __expf(-v)); }
__device__ __forceinline__ unsigned short f2bf(float v) {
    __bf16 b = (__bf16)v;
    return __builtin_bit_cast(unsigned short, b);
}
// bf16 pair unpack: lo/hi halves of a dword -> f32 (1 inst each)
__device__ __forceinline__ float blo(unsigned d) { return __builtin_bit_cast(float, d << 16); }
__device__ __forceinline__ float bhi(unsigned d) { return __builtin_bit_cast(float, d & 0xffff0000u); }

// ---------------------------------------------------------------------------
// K0: pack weights into MFMA B-fragment layouts (bf16) + biases.
//   Tap-major K-order: k = ktap*64 + c.
//   wB [br][kgrp][o(64)][j],  owB[br][kgrp][o(32)][j] (o>=27 zero-padded)
// ---------------------------------------------------------------------------
__global__ __launch_bounds__(256) void k0_prep(Params p) {
    int i = blockIdx.x * 256 + threadIdx.x;
    unsigned short* wb  = (unsigned short*)(p.ws + WS_WB);
    unsigned short* owb = (unsigned short*)(p.ws + WS_OWB);
    if (i < 294912) {
        int br = i / 36864; int r = i % 36864;
        int kgrp = r >> 9; int o = (r >> 3) & 63; int j = r & 7;
        int k = kgrp * 8 + j;
        int ktap = k >> 6; int c = k & 63;
        wb[i] = f2bf(p.w[br][(o * 64 + c) * 9 + ktap]);
    } else if (i < 294912 + 147456) {
        int ii = i - 294912;
        int br = ii / 18432; int r = ii % 18432;
        int kgrp = r >> 8; int o = (r >> 3) & 31; int j = r & 7;
        int k = kgrp * 8 + j;
        int ktap = k >> 6; int c = k & 63;
        float v = (o < 27) ? p.ow[br][(o * 64 + c) * 9 + ktap] : 0.f;
        owb[ii] = f2bf(v);
    } else if (i < 294912 + 147456 + 216) {
        int ii = i - 442368;
        int br = ii / 27; int j = ii % 27;
        p.ws[WS_OB + ii] = p.ob[br][j];
    }
}

// ---------------------------------------------------------------------------
// K0T: CHW fp32 -> HWC bf16 transpose of x and h.
// ---------------------------------------------------------------------------
__global__ __launch_bounds__(256) void k0_transp(Params p) {
    __shared__ float tile[64][65];
    int bid = blockIdx.x;
    int row = bid & 63; int b = (bid >> 6) & 7; int ten = bid >> 9;
    const float* src = ten ? p.h : p.x;
    unsigned short* dst = (unsigned short*)(p.ws + (ten ? WS_HT : WS_XT));
    int t = threadIdx.x; int lane = t & 63; int w4 = t >> 6;
#pragma unroll
    for (int i = 0; i < 16; ++i) {
        int c = i * 4 + w4;
        tile[c][lane] = src[((size_t)(b * 64 + c) << 12) + row * 64 + lane];
    }
    __syncthreads();
#pragma unroll
    for (int i = 0; i < 16; ++i) {
        int px = i * 4 + w4;
        dst[((size_t)(b * 4096 + row * 64 + px) << 6) + lane] = f2bf(tile[lane][px]);
    }
}

// ---------------------------------------------------------------------------
// K2 v6 (fused, spill-fixed): offset-conv + deform gather + MFMA reduce.
//   grid: gate(4) * row(64) * b(8) = 2048 blocks of 256. Wave = px-tile.
//   __launch_bounds__(256,4): VGPR cap 128 — v5's (256,6) capped at ~85 and
//   spilled the accumulators (1.6 GB scratch traffic, VGPR_Count=40).
//   LDS arena 22272 B: rb(8448) aliases sA(4608)+sW(9216); sOff(8448) after.
// ---------------------------------------------------------------------------
__global__ __launch_bounds__(256, 4) void k2_fused(Params p) {
    __shared__ __align__(16) unsigned char arena[22272];
    unsigned short* rb = (unsigned short*)arena;            // [cg][px+2][8] bf16
    uint2*  sA   = (uint2*)arena;                           // [9][64]
    float4* sWp  = (float4*)(arena + 4608);                 // [9][64]
    float*  sOff = (float*)(arena + 13824);                 // [32][66]

    int bid = blockIdx.x;
    int gate = bid & 3; int row = (bid >> 2) & 63; int b = bid >> 8;
    int t = threadIdx.x; int l = t & 63; int w = t >> 6;
    int q = l >> 4; int n = l & 15;
    int pxl = w * 16 + n;

    const unsigned short* wBp = (const unsigned short*)(p.ws + WS_WB);
    const unsigned short* owb = (const unsigned short*)(p.ws + WS_OWB);

    f32x4 acc[4];
#pragma unroll
    for (int ot = 0; ot < 4; ++ot) acc[ot] = (f32x4){0.f, 0.f, 0.f, 0.f};

    for (int sub = 0; sub < 2; ++sub) {
        int br = gate * 2 + sub;
        const unsigned short* inT =
            (const unsigned short*)(p.ws + (sub ? WS_HT : WS_XT)) + ((size_t)b << 18);
        const float* obp = p.ws + WS_OB + br * 27;

        // ---- fused offset conv: M=16 px (this wave's tile), N=32, K=576 ----
        f32x4 acc2[2];
        acc2[0] = (f32x4){0.f, 0.f, 0.f, 0.f};
        acc2[1] = (f32x4){0.f, 0.f, 0.f, 0.f};
        for (int dy = 0; dy < 3; ++dy) {
            int srow = row + dy - 1;
            __syncthreads();          // rb region free (prev phase/iter done)
#pragma unroll
            for (int ii = 0; ii < 3; ++ii) {
                int unit = t + ii * 256;
                if (unit < 528) {
                    int pxi = unit >> 3; int cg = unit & 7; int spx = pxi - 1;
                    uint4 v = {0u, 0u, 0u, 0u};
                    if (((unsigned)srow < 64u) && ((unsigned)spx < 64u))
                        v = *(const uint4*)(inT + (((size_t)srow * 64 + spx) << 6) + cg * 8);
                    *(uint4*)(rb + (cg * 66 + pxi) * 8) = v;
                }
            }
            __syncthreads();
#pragma unroll
            for (int s = 0; s < 6; ++s) {
                int dxk = s >> 1; int cgb = (s & 1) * 4 + q;
                bf16x8 af = *(const bf16x8*)(rb + (cgb * 66 + w * 16 + n + dxk) * 8);
                int kb = (br * 72 + dy * 24 + s * 4 + q) * 32;
#pragma unroll
                for (int ot = 0; ot < 2; ++ot) {
                    bf16x8 bfg = *(const bf16x8*)(owb + (size_t)(kb + ot * 16 + n) * 8);
                    acc2[ot] = __builtin_amdgcn_mfma_f32_16x16x32_bf16(af, bfg, acc2[ot], 0, 0, 0);
                }
            }
        }
        // D-frags (+bias) -> sOff[j][px]; j=ot*16+n, px=w*16+q*4+r
#pragma unroll
        for (int ot = 0; ot < 2; ++ot) {
            int j = ot * 16 + n;
            float bias = (j < 27) ? obp[j] : 0.f;
#pragma unroll
            for (int r = 0; r < 4; ++r)
                sOff[j * 66 + w * 16 + q * 4 + r] = acc2[ot][r] + bias;
        }
        __syncthreads();   // sOff visible; rb dead -> sA/sW writable

        // ---- Phase A: bilinear coords + (mask*inbound)-folded weights ----
        for (int i2 = t; i2 < 576; i2 += 256) {
            int px = i2 & 63; int k = i2 >> 6;
            float dy = sOff[(2 * k) * 66 + px];
            float dx = sOff[(2 * k + 1) * 66 + px];
            float mm = sOff[(18 + k) * 66 + px];
            float m = sigf(mm);
            int ki = k / 3, kj = k % 3;
            float py  = (float)(row + ki - 1) + dy;
            float pxx = (float)(px + kj - 1) + dx;
            float y0f = floorf(py), x0f = floorf(pxx);
            float wy = py - y0f, wx = pxx - x0f;
            int y0 = (int)y0f, x0 = (int)x0f;
            float y0i = ((unsigned)y0 < 64u) ? 1.f : 0.f;
            float y1i = ((unsigned)(y0 + 1) < 64u) ? 1.f : 0.f;
            float x0i = ((unsigned)x0 < 64u) ? 1.f : 0.f;
            float x1i = ((unsigned)(x0 + 1) < 64u) ? 1.f : 0.f;
            float w00 = (1.f - wy) * (1.f - wx) * m * y0i * x0i;
            float w01 = (1.f - wy) * wx         * m * y0i * x1i;
            float w10 = wy         * (1.f - wx) * m * y1i * x0i;
            float w11 = wy         * wx         * m * y1i * x1i;
            int cy0 = min(max(y0, 0), 63),     cy1 = min(max(y0 + 1, 0), 63);
            int cx0 = min(max(x0, 0), 63),     cx1 = min(max(x0 + 1, 0), 63);
            sA[k * 64 + px] = make_uint2((unsigned)(cy0 * 64 + cx0) | ((unsigned)(cy0 * 64 + cx1) << 16),
                                         (unsigned)(cy1 * 64 + cx0) | ((unsigned)(cy1 * 64 + cx1) << 16));
            sWp[k * 64 + px] = make_float4(w00, w01, w10, w11);
        }
        __syncthreads();

        // ---- gather directly into A-frags + main MFMA ----
        const unsigned short* cbase = inT + q * 8;
#pragma unroll 3
        for (int ktap = 0; ktap < 9; ++ktap) {
            uint2 aa = sA[ktap * 64 + pxl];
            float4 wv = sWp[ktap * 64 + pxl];
            unsigned i0 = (aa.x & 0xffffu) << 6;
            unsigned i1 = (aa.x >> 16) << 6;
            unsigned i2 = (aa.y & 0xffffu) << 6;
            unsigned i3 = (aa.y >> 16) << 6;
#pragma unroll
            for (int half = 0; half < 2; ++half) {
                int s = ktap * 2 + half;
                const unsigned short* cb = cbase + half * 32;
                uint4 A0 = *(const uint4*)(cb + i0);
                uint4 A1 = *(const uint4*)(cb + i1);
                uint4 A2 = *(const uint4*)(cb + i2);
                uint4 A3 = *(const uint4*)(cb + i3);
                bf16x8 af;
#define COMB(m, d0, d1, d2, d3)                                                   \
                af[2*m]   = (__bf16)(wv.x*blo(d0) + wv.y*blo(d1) + wv.z*blo(d2) + wv.w*blo(d3)); \
                af[2*m+1] = (__bf16)(wv.x*bhi(d0) + wv.y*bhi(d1) + wv.z*bhi(d2) + wv.w*bhi(d3));
                COMB(0, A0.x, A1.x, A2.x, A3.x)
                COMB(1, A0.y, A1.y, A2.y, A3.y)
                COMB(2, A0.z, A1.z, A2.z, A3.z)
                COMB(3, A0.w, A1.w, A2.w, A3.w)
#undef COMB
                int kb = (br * 72 + s * 4 + q) * 64;
#pragma unroll
                for (int ot = 0; ot < 4; ++ot) {
                    bf16x8 bfg = *(const bf16x8*)(wBp + (size_t)(kb + ot * 16 + n) * 8);
                    acc[ot] = __builtin_amdgcn_mfma_f32_16x16x32_bf16(af, bfg, acc[ot], 0, 0, 0);
                }
            }
        }
        __syncthreads();   // protect sA/sW/arena before next sub's rb staging
    }

    // epilogue: direct D-scrambled coalesced store; K3 decodes.
    float* gp = p.ws + WS_GATES + ((size_t)((gate * 8 + b) * 64 + row) << 12);
#pragma unroll
    for (int ot = 0; ot < 4; ++ot)
        *(float4*)(gp + ((w * 4 + ot) * 64 + l) * 4) = *(float4*)&acc[ot];
}

// ---------------------------------------------------------------------------
// K3: pointwise ConvLSTM combine, reading D-scrambled gates (coalesced) and
//   decoding (o,px) for c/out access (16B-segment granularity).
//   grid: 8192 blocks of 256.
// ---------------------------------------------------------------------------
__global__ __launch_bounds__(256) void k3_lstm(Params p) {
    int T = blockIdx.x * 256 + threadIdx.x;        // [b][row][i] over scrambled
    int i = T & 4095; int row = (T >> 12) & 63; int b = T >> 18;
    const float* gp = p.ws + WS_GATES;
    size_t base = ((size_t)(b * 64 + row) << 12) + i;
    float gi = gp[base];
    float gf = gp[base + 1 * PLANE];
    float gc = gp[base + 2 * PLANE];
    float go = gp[base + 3 * PLANE];
    // decode scramble: i = ((w*4+ot)*64 + l)*4 + r
    int r = i & 3; int l = (i >> 2) & 63; int u = i >> 8;
    int w = u >> 2; int ot = u & 3;
    int o = ot * 16 + (l & 15);
    int px = w * 16 + (l >> 4) * 4 + r;
    size_t cidx = ((size_t)(b * 64 + o) << 12) + row * 64 + px;
    float cold = p.c[cidx];
    float ig = sigf(gi + cold * p.wci[o] + p.bi[o]);
    float fg = sigf(gf + cold * p.wcf[o] + p.bf[o]);
    float cn = fg * cold + ig * tanhf(gc + p.bc[o]);
    float og = sigf(go + cn * p.wco[o] + p.bo[o]);
    p.out[cidx] = og * tanhf(cn);
    p.out[cidx + PLANE] = cn;
}

// ---------------------------------------------------------------------------
extern "C" void kernel_launch(void* const* d_in, const int* in_sizes, int n_in,
                              void* d_out, int out_size, void* d_ws, size_t ws_size,
                              hipStream_t stream) {
    (void)in_sizes; (void)n_in; (void)out_size; (void)ws_size;
    Params P;
    P.x = (const float*)d_in[0];
    P.h = (const float*)d_in[1];
    P.c = (const float*)d_in[2];
    for (int i = 0; i < 8; ++i) {
        P.w[i]  = (const float*)d_in[3 + 3 * i];
        P.ow[i] = (const float*)d_in[4 + 3 * i];
        P.ob[i] = (const float*)d_in[5 + 3 * i];
    }
    P.bi  = (const float*)d_in[27];
    P.bf  = (const float*)d_in[28];
    P.bc  = (const float*)d_in[29];
    P.bo  = (const float*)d_in[30];
    P.wci = (const float*)d_in[31];
    P.wcf = (const float*)d_in[32];
    P.wco = (const float*)d_in[33];
    P.out = (float*)d_out;
    P.ws  = (float*)d_ws;

    k0_prep   <<<dim3(1729), dim3(256), 0, stream>>>(P);
    k0_transp <<<dim3(1024), dim3(256), 0, stream>>>(P);
    k2_fused  <<<dim3(2048), dim3(256), 0, stream>>>(P);
    k3_lstm   <<<dim3(8192), dim3(256), 0, stream>>>(P);
}

// Round 7
// 363.000 us; speedup vs baseline: 1.7297x; 1.0586x over previous
//
#include <hip/hip_runtime.h>
#include <math.h>

// Problem constants (B=8, Cin=Cout=64, H=W=64, 3x3 kernel pad 1)
#define NB     8
#define NC     64
#define HW     4096           // 64*64
#define PLANE  2097152        // NB*NC*HW

// Workspace layout (float-slot offsets)
#define WS_WB     0           // bf16 wB[8][72][64][8]   (294912 bf16 = 147456 f)
#define WS_OWB    147456      // bf16 owB[8][72][32][8]  (147456 bf16 = 73728 f)
#define WS_OB     221184      // f32 obAll[8][27]
#define WS_GATES  221400      // f32 gates_scr[4][8][64][4096] = 8388608 (D-scrambled)
#define WS_XT     8610008     // bf16 xT[8][4096][64] HWC  (1048576 f)
#define WS_HT     9658584     // bf16 hT[8][4096][64] HWC  (1048576 f)
// total = 10707160 floats = 42.8 MB

typedef __bf16 bf16x8 __attribute__((ext_vector_type(8)));
typedef float  f32x4  __attribute__((ext_vector_type(4)));

struct Params {
    const float* x; const float* h; const float* c;
    const float* w[8]; const float* ow[8]; const float* ob[8];
    const float* bi; const float* bf; const float* bc; const float* bo;
    const float* wci; const float* wcf; const float* wco;
    float* out; float* ws;
};

__device__ __forceinline__ float sigf(float v) { return 1.f / (1.f + __expf(-v)); }
__device__ __forceinline__ unsigned short f2bf(float v) {
    __bf16 b = (__bf16)v;
    return __builtin_bit_cast(unsigned short, b);
}
// bf16 pair unpack: lo/hi halves of a dword -> f32 (1 inst each)
__device__ __forceinline__ float blo(unsigned d) { return __builtin_bit_cast(float, d << 16); }
__device__ __forceinline__ float bhi(unsigned d) { return __builtin_bit_cast(float, d & 0xffff0000u); }

// ---------------------------------------------------------------------------
// K0: pack weights into MFMA B-fragment layouts (bf16) + biases.
//   Tap-major K-order: k = ktap*64 + c.
//   wB [br][kgrp][o(64)][j],  owB[br][kgrp][o(32)][j] (o>=27 zero-padded)
// ---------------------------------------------------------------------------
__global__ __launch_bounds__(256) void k0_prep(Params p) {
    int i = blockIdx.x * 256 + threadIdx.x;
    unsigned short* wb  = (unsigned short*)(p.ws + WS_WB);
    unsigned short* owb = (unsigned short*)(p.ws + WS_OWB);
    if (i < 294912) {
        int br = i / 36864; int r = i % 36864;
        int kgrp = r >> 9; int o = (r >> 3) & 63; int j = r & 7;
        int k = kgrp * 8 + j;
        int ktap = k >> 6; int c = k & 63;
        wb[i] = f2bf(p.w[br][(o * 64 + c) * 9 + ktap]);
    } else if (i < 294912 + 147456) {
        int ii = i - 294912;
        int br = ii / 18432; int r = ii % 18432;
        int kgrp = r >> 8; int o = (r >> 3) & 31; int j = r & 7;
        int k = kgrp * 8 + j;
        int ktap = k >> 6; int c = k & 63;
        float v = (o < 27) ? p.ow[br][(o * 64 + c) * 9 + ktap] : 0.f;
        owb[ii] = f2bf(v);
    } else if (i < 294912 + 147456 + 216) {
        int ii = i - 442368;
        int br = ii / 27; int j = ii % 27;
        p.ws[WS_OB + ii] = p.ob[br][j];
    }
}

// ---------------------------------------------------------------------------
// K0T: CHW fp32 -> HWC bf16 transpose of x and h.
// ---------------------------------------------------------------------------
__global__ __launch_bounds__(256) void k0_transp(Params p) {
    __shared__ float tile[64][65];
    int bid = blockIdx.x;
    int row = bid & 63; int b = (bid >> 6) & 7; int ten = bid >> 9;
    const float* src = ten ? p.h : p.x;
    unsigned short* dst = (unsigned short*)(p.ws + (ten ? WS_HT : WS_XT));
    int t = threadIdx.x; int lane = t & 63; int w4 = t >> 6;
#pragma unroll
    for (int i = 0; i < 16; ++i) {
        int c = i * 4 + w4;
        tile[c][lane] = src[((size_t)(b * 64 + c) << 12) + row * 64 + lane];
    }
    __syncthreads();
#pragma unroll
    for (int i = 0; i < 16; ++i) {
        int px = i * 4 + w4;
        dst[((size_t)(b * 4096 + row * 64 + px) << 6) + lane] = f2bf(tile[lane][px]);
    }
}

// ---------------------------------------------------------------------------
// K2 v7 (fused, pressure-fixed): offset-conv + deform gather + MFMA reduce.
//   grid: gate(4) * row(64) * b(8) = 2048 blocks of 256. Wave = px-tile.
//   vs v6: removed ktap unroll-3 (it tripled live corner regs -> spill;
//   WRITE_SIZE 226 MB vs 37 MB ideal), corner combine is now sequential
//   (one uint4 live at a time).  __launch_bounds__(256,4).
//   LDS arena 22272 B: rb(8448) aliases sA(4608)+sW(9216); sOff(8448) after.
// ---------------------------------------------------------------------------
__global__ __launch_bounds__(256, 4) void k2_fused(Params p) {
    __shared__ __align__(16) unsigned char arena[22272];
    unsigned short* rb = (unsigned short*)arena;            // [cg][px+2][8] bf16
    uint2*  sA   = (uint2*)arena;                           // [9][64]
    float4* sWp  = (float4*)(arena + 4608);                 // [9][64]
    float*  sOff = (float*)(arena + 13824);                 // [32][66]

    int bid = blockIdx.x;
    int gate = bid & 3; int row = (bid >> 2) & 63; int b = bid >> 8;
    int t = threadIdx.x; int l = t & 63; int w = t >> 6;
    int q = l >> 4; int n = l & 15;
    int pxl = w * 16 + n;

    const unsigned short* wBp = (const unsigned short*)(p.ws + WS_WB);
    const unsigned short* owb = (const unsigned short*)(p.ws + WS_OWB);

    f32x4 acc[4];
#pragma unroll
    for (int ot = 0; ot < 4; ++ot) acc[ot] = (f32x4){0.f, 0.f, 0.f, 0.f};

    for (int sub = 0; sub < 2; ++sub) {
        int br = gate * 2 + sub;
        const unsigned short* inT =
            (const unsigned short*)(p.ws + (sub ? WS_HT : WS_XT)) + ((size_t)b << 18);
        const float* obp = p.ws + WS_OB + br * 27;

        // ---- fused offset conv: M=16 px (this wave's tile), N=32, K=576 ----
        f32x4 acc2[2];
        acc2[0] = (f32x4){0.f, 0.f, 0.f, 0.f};
        acc2[1] = (f32x4){0.f, 0.f, 0.f, 0.f};
        for (int dy = 0; dy < 3; ++dy) {
            int srow = row + dy - 1;
            __syncthreads();          // rb region free (prev phase/iter done)
#pragma unroll
            for (int ii = 0; ii < 3; ++ii) {
                int unit = t + ii * 256;
                if (unit < 528) {
                    int pxi = unit >> 3; int cg = unit & 7; int spx = pxi - 1;
                    uint4 v = {0u, 0u, 0u, 0u};
                    if (((unsigned)srow < 64u) && ((unsigned)spx < 64u))
                        v = *(const uint4*)(inT + (((size_t)srow * 64 + spx) << 6) + cg * 8);
                    *(uint4*)(rb + (cg * 66 + pxi) * 8) = v;
                }
            }
            __syncthreads();
#pragma unroll
            for (int s = 0; s < 6; ++s) {
                int dxk = s >> 1; int cgb = (s & 1) * 4 + q;
                bf16x8 af = *(const bf16x8*)(rb + (cgb * 66 + w * 16 + n + dxk) * 8);
                int kb = (br * 72 + dy * 24 + s * 4 + q) * 32;
#pragma unroll
                for (int ot = 0; ot < 2; ++ot) {
                    bf16x8 bfg = *(const bf16x8*)(owb + (size_t)(kb + ot * 16 + n) * 8);
                    acc2[ot] = __builtin_amdgcn_mfma_f32_16x16x32_bf16(af, bfg, acc2[ot], 0, 0, 0);
                }
            }
        }
        // D-frags (+bias) -> sOff[j][px]; j=ot*16+n, px=w*16+q*4+r
#pragma unroll
        for (int ot = 0; ot < 2; ++ot) {
            int j = ot * 16 + n;
            float bias = (j < 27) ? obp[j] : 0.f;
#pragma unroll
            for (int r = 0; r < 4; ++r)
                sOff[j * 66 + w * 16 + q * 4 + r] = acc2[ot][r] + bias;
        }
        __syncthreads();   // sOff visible; rb dead -> sA/sW writable

        // ---- Phase A: bilinear coords + (mask*inbound)-folded weights ----
        for (int i2 = t; i2 < 576; i2 += 256) {
            int px = i2 & 63; int k = i2 >> 6;
            float dy = sOff[(2 * k) * 66 + px];
            float dx = sOff[(2 * k + 1) * 66 + px];
            float mm = sOff[(18 + k) * 66 + px];
            float m = sigf(mm);
            int ki = k / 3, kj = k % 3;
            float py  = (float)(row + ki - 1) + dy;
            float pxx = (float)(px + kj - 1) + dx;
            float y0f = floorf(py), x0f = floorf(pxx);
            float wy = py - y0f, wx = pxx - x0f;
            int y0 = (int)y0f, x0 = (int)x0f;
            float y0i = ((unsigned)y0 < 64u) ? 1.f : 0.f;
            float y1i = ((unsigned)(y0 + 1) < 64u) ? 1.f : 0.f;
            float x0i = ((unsigned)x0 < 64u) ? 1.f : 0.f;
            float x1i = ((unsigned)(x0 + 1) < 64u) ? 1.f : 0.f;
            float w00 = (1.f - wy) * (1.f - wx) * m * y0i * x0i;
            float w01 = (1.f - wy) * wx         * m * y0i * x1i;
            float w10 = wy         * (1.f - wx) * m * y1i * x0i;
            float w11 = wy         * wx         * m * y1i * x1i;
            int cy0 = min(max(y0, 0), 63),     cy1 = min(max(y0 + 1, 0), 63);
            int cx0 = min(max(x0, 0), 63),     cx1 = min(max(x0 + 1, 0), 63);
            sA[k * 64 + px] = make_uint2((unsigned)(cy0 * 64 + cx0) | ((unsigned)(cy0 * 64 + cx1) << 16),
                                         (unsigned)(cy1 * 64 + cx0) | ((unsigned)(cy1 * 64 + cx1) << 16));
            sWp[k * 64 + px] = make_float4(w00, w01, w10, w11);
        }
        __syncthreads();

        // ---- gather directly into A-frags + main MFMA ----
        const unsigned short* cbase = inT + q * 8;
        for (int ktap = 0; ktap < 9; ++ktap) {
            uint2 aa = sA[ktap * 64 + pxl];
            float4 wv = sWp[ktap * 64 + pxl];
            unsigned i0 = (aa.x & 0xffffu) << 6;
            unsigned i1 = (aa.x >> 16) << 6;
            unsigned i2 = (aa.y & 0xffffu) << 6;
            unsigned i3 = (aa.y >> 16) << 6;
#pragma unroll
            for (int half = 0; half < 2; ++half) {
                int s = ktap * 2 + half;
                const unsigned short* cb = cbase + half * 32;
                // sequential corner accumulation: one uint4 live at a time
                float sacc[8];
                {
                    uint4 A = *(const uint4*)(cb + i0);
                    sacc[0] = wv.x * blo(A.x); sacc[1] = wv.x * bhi(A.x);
                    sacc[2] = wv.x * blo(A.y); sacc[3] = wv.x * bhi(A.y);
                    sacc[4] = wv.x * blo(A.z); sacc[5] = wv.x * bhi(A.z);
                    sacc[6] = wv.x * blo(A.w); sacc[7] = wv.x * bhi(A.w);
                }
                {
                    uint4 A = *(const uint4*)(cb + i1);
                    sacc[0] += wv.y * blo(A.x); sacc[1] += wv.y * bhi(A.x);
                    sacc[2] += wv.y * blo(A.y); sacc[3] += wv.y * bhi(A.y);
                    sacc[4] += wv.y * blo(A.z); sacc[5] += wv.y * bhi(A.z);
                    sacc[6] += wv.y * blo(A.w); sacc[7] += wv.y * bhi(A.w);
                }
                {
                    uint4 A = *(const uint4*)(cb + i2);
                    sacc[0] += wv.z * blo(A.x); sacc[1] += wv.z * bhi(A.x);
                    sacc[2] += wv.z * blo(A.y); sacc[3] += wv.z * bhi(A.y);
                    sacc[4] += wv.z * blo(A.z); sacc[5] += wv.z * bhi(A.z);
                    sacc[6] += wv.z * blo(A.w); sacc[7] += wv.z * bhi(A.w);
                }
                {
                    uint4 A = *(const uint4*)(cb + i3);
                    sacc[0] += wv.w * blo(A.x); sacc[1] += wv.w * bhi(A.x);
                    sacc[2] += wv.w * blo(A.y); sacc[3] += wv.w * bhi(A.y);
                    sacc[4] += wv.w * blo(A.z); sacc[5] += wv.w * bhi(A.z);
                    sacc[6] += wv.w * blo(A.w); sacc[7] += wv.w * bhi(A.w);
                }
                bf16x8 af;
#pragma unroll
                for (int j = 0; j < 8; ++j) af[j] = (__bf16)sacc[j];
                int kb = (br * 72 + s * 4 + q) * 64;
#pragma unroll
                for (int ot = 0; ot < 4; ++ot) {
                    bf16x8 bfg = *(const bf16x8*)(wBp + (size_t)(kb + ot * 16 + n) * 8);
                    acc[ot] = __builtin_amdgcn_mfma_f32_16x16x32_bf16(af, bfg, acc[ot], 0, 0, 0);
                }
            }
        }
        __syncthreads();   // protect sA/sW/arena before next sub's rb staging
    }

    // epilogue: direct D-scrambled coalesced store; K3 decodes.
    float* gp = p.ws + WS_GATES + ((size_t)((gate * 8 + b) * 64 + row) << 12);
#pragma unroll
    for (int ot = 0; ot < 4; ++ot)
        *(float4*)(gp + ((w * 4 + ot) * 64 + l) * 4) = *(float4*)&acc[ot];
}

// ---------------------------------------------------------------------------
// K3: pointwise ConvLSTM combine, reading D-scrambled gates (coalesced) and
//   decoding (o,px) for c/out access (16B-segment granularity).
//   grid: 8192 blocks of 256.
// ---------------------------------------------------------------------------
__global__ __launch_bounds__(256) void k3_lstm(Params p) {
    int T = blockIdx.x * 256 + threadIdx.x;        // [b][row][i] over scrambled
    int i = T & 4095; int row = (T >> 12) & 63; int b = T >> 18;
    const float* gp = p.ws + WS_GATES;
    size_t base = ((size_t)(b * 64 + row) << 12) + i;
    float gi = gp[base];
    float gf = gp[base + 1 * PLANE];
    float gc = gp[base + 2 * PLANE];
    float go = gp[base + 3 * PLANE];
    // decode scramble: i = ((w*4+ot)*64 + l)*4 + r
    int r = i & 3; int l = (i >> 2) & 63; int u = i >> 8;
    int w = u >> 2; int ot = u & 3;
    int o = ot * 16 + (l & 15);
    int px = w * 16 + (l >> 4) * 4 + r;
    size_t cidx = ((size_t)(b * 64 + o) << 12) + row * 64 + px;
    float cold = p.c[cidx];
    float ig = sigf(gi + cold * p.wci[o] + p.bi[o]);
    float fg = sigf(gf + cold * p.wcf[o] + p.bf[o]);
    float cn = fg * cold + ig * tanhf(gc + p.bc[o]);
    float og = sigf(go + cn * p.wco[o] + p.bo[o]);
    p.out[cidx] = og * tanhf(cn);
    p.out[cidx + PLANE] = cn;
}

// ---------------------------------------------------------------------------
extern "C" void kernel_launch(void* const* d_in, const int* in_sizes, int n_in,
                              void* d_out, int out_size, void* d_ws, size_t ws_size,
                              hipStream_t stream) {
    (void)in_sizes; (void)n_in; (void)out_size; (void)ws_size;
    Params P;
    P.x = (const float*)d_in[0];
    P.h = (const float*)d_in[1];
    P.c = (const float*)d_in[2];
    for (int i = 0; i < 8; ++i) {
        P.w[i]  = (const float*)d_in[3 + 3 * i];
        P.ow[i] = (const float*)d_in[4 + 3 * i];
        P.ob[i] = (const float*)d_in[5 + 3 * i];
    }
    P.bi  = (const float*)d_in[27];
    P.bf  = (const float*)d_in[28];
    P.bc  = (const float*)d_in[29];
    P.bo  = (const float*)d_in[30];
    P.wci = (const float*)d_in[31];
    P.wcf = (const float*)d_in[32];
    P.wco = (const float*)d_in[33];
    P.out = (float*)d_out;
    P.ws  = (float*)d_ws;

    k0_prep   <<<dim3(1729), dim3(256), 0, stream>>>(P);
    k0_transp <<<dim3(1024), dim3(256), 0, stream>>>(P);
    k2_fused  <<<dim3(2048), dim3(256), 0, stream>>>(P);
    k3_lstm   <<<dim3(8192), dim3(256), 0, stream>>>(P);
}

// Round 8
// 358.097 us; speedup vs baseline: 1.7534x; 1.0137x over previous
//
#include <hip/hip_runtime.h>
#include <math.h>

// Problem constants (B=8, Cin=Cout=64, H=W=64, 3x3 kernel pad 1)
#define NB     8
#define NC     64
#define HW     4096           // 64*64
#define PLANE  2097152        // NB*NC*HW

// Workspace layout (float-slot offsets)
#define WS_WB     0           // bf16 wB[8][72][64][8]   (294912 bf16 = 147456 f)
#define WS_OWB    147456      // bf16 owB[8][72][32][8]  (147456 bf16 = 73728 f)
#define WS_OB     221184      // f32 obAll[8][27]
#define WS_GATES  221400      // f32 gates_scr[4][8][64][4096] = 8388608 (D-scrambled)
#define WS_XT     8610008     // bf16 xT[8][4096][64] HWC  (1048576 f)
#define WS_HT     9658584     // bf16 hT[8][4096][64] HWC  (1048576 f)
// total = 10707160 floats = 42.8 MB

typedef __bf16 bf16x8 __attribute__((ext_vector_type(8)));
typedef float  f32x4  __attribute__((ext_vector_type(4)));

struct Params {
    const float* x; const float* h; const float* c;
    const float* w[8]; const float* ow[8]; const float* ob[8];
    const float* bi; const float* bf; const float* bc; const float* bo;
    const float* wci; const float* wcf; const float* wco;
    float* out; float* ws;
};

__device__ __forceinline__ float sigf(float v) { return 1.f / (1.f + __expf(-v)); }
__device__ __forceinline__ unsigned short f2bf(float v) {
    __bf16 b = (__bf16)v;
    return __builtin_bit_cast(unsigned short, b);
}
// bf16 pair unpack: lo/hi halves of a dword -> f32 (1 inst each)
__device__ __forceinline__ float blo(unsigned d) { return __builtin_bit_cast(float, d << 16); }
__device__ __forceinline__ float bhi(unsigned d) { return __builtin_bit_cast(float, d & 0xffff0000u); }

// ---------------------------------------------------------------------------
// K0: pack weights into MFMA B-fragment layouts (bf16) + biases.
//   Tap-major K-order: k = ktap*64 + c.
//   wB [br][kgrp][o(64)][j],  owB[br][kgrp][o(32)][j] (o>=27 zero-padded)
// ---------------------------------------------------------------------------
__global__ __launch_bounds__(256) void k0_prep(Params p) {
    int i = blockIdx.x * 256 + threadIdx.x;
    unsigned short* wb  = (unsigned short*)(p.ws + WS_WB);
    unsigned short* owb = (unsigned short*)(p.ws + WS_OWB);
    if (i < 294912) {
        int br = i / 36864; int r = i % 36864;
        int kgrp = r >> 9; int o = (r >> 3) & 63; int j = r & 7;
        int k = kgrp * 8 + j;
        int ktap = k >> 6; int c = k & 63;
        wb[i] = f2bf(p.w[br][(o * 64 + c) * 9 + ktap]);
    } else if (i < 294912 + 147456) {
        int ii = i - 294912;
        int br = ii / 18432; int r = ii % 18432;
        int kgrp = r >> 8; int o = (r >> 3) & 31; int j = r & 7;
        int k = kgrp * 8 + j;
        int ktap = k >> 6; int c = k & 63;
        float v = (o < 27) ? p.ow[br][(o * 64 + c) * 9 + ktap] : 0.f;
        owb[ii] = f2bf(v);
    } else if (i < 294912 + 147456 + 216) {
        int ii = i - 442368;
        int br = ii / 27; int j = ii % 27;
        p.ws[WS_OB + ii] = p.ob[br][j];
    }
}

// ---------------------------------------------------------------------------
// K0T: CHW fp32 -> HWC bf16 transpose of x and h.
// ---------------------------------------------------------------------------
__global__ __launch_bounds__(256) void k0_transp(Params p) {
    __shared__ float tile[64][65];
    int bid = blockIdx.x;
    int row = bid & 63; int b = (bid >> 6) & 7; int ten = bid >> 9;
    const float* src = ten ? p.h : p.x;
    unsigned short* dst = (unsigned short*)(p.ws + (ten ? WS_HT : WS_XT));
    int t = threadIdx.x; int lane = t & 63; int w4 = t >> 6;
#pragma unroll
    for (int i = 0; i < 16; ++i) {
        int c = i * 4 + w4;
        tile[c][lane] = src[((size_t)(b * 64 + c) << 12) + row * 64 + lane];
    }
    __syncthreads();
#pragma unroll
    for (int i = 0; i < 16; ++i) {
        int px = i * 4 + w4;
        dst[((size_t)(b * 4096 + row * 64 + px) << 6) + lane] = f2bf(tile[lane][px]);
    }
}

// ---------------------------------------------------------------------------
// K2 v8 (fused): offset-conv + deform gather + MFMA reduce.
//   grid: gate(4) * row(64) * b(8) = 2048 blocks of 256. Wave = px-tile.
//   __launch_bounds__(256,3): v7's (256,4) capped total regs at 128 and the
//   compiler split 64 arch / 64 accum -> arch side spilled ~88 MB/dispatch
//   (WRITE 121 MB vs 33.5 ideal, VGPR_Count stuck at 64). Cap ~168 gives the
//   arch side ~128 while guaranteeing 3 waves/SIMD (LDS 22.3 KB not binding).
//   LDS arena 22272 B: rb(8448) aliases sA(4608)+sW(9216); sOff(8448) after.
// ---------------------------------------------------------------------------
__global__ __launch_bounds__(256, 3) void k2_fused(Params p) {
    __shared__ __align__(16) unsigned char arena[22272];
    unsigned short* rb = (unsigned short*)arena;            // [cg][px+2][8] bf16
    uint2*  sA   = (uint2*)arena;                           // [9][64]
    float4* sWp  = (float4*)(arena + 4608);                 // [9][64]
    float*  sOff = (float*)(arena + 13824);                 // [32][66]

    int bid = blockIdx.x;
    int gate = bid & 3; int row = (bid >> 2) & 63; int b = bid >> 8;
    int t = threadIdx.x; int l = t & 63; int w = t >> 6;
    int q = l >> 4; int n = l & 15;
    int pxl = w * 16 + n;

    const unsigned short* wBp = (const unsigned short*)(p.ws + WS_WB);
    const unsigned short* owb = (const unsigned short*)(p.ws + WS_OWB);

    f32x4 acc[4];
#pragma unroll
    for (int ot = 0; ot < 4; ++ot) acc[ot] = (f32x4){0.f, 0.f, 0.f, 0.f};

    for (int sub = 0; sub < 2; ++sub) {
        int br = gate * 2 + sub;
        const unsigned short* inT =
            (const unsigned short*)(p.ws + (sub ? WS_HT : WS_XT)) + ((size_t)b << 18);
        const float* obp = p.ws + WS_OB + br * 27;

        // ---- fused offset conv: M=16 px (this wave's tile), N=32, K=576 ----
        f32x4 acc2[2];
        acc2[0] = (f32x4){0.f, 0.f, 0.f, 0.f};
        acc2[1] = (f32x4){0.f, 0.f, 0.f, 0.f};
        for (int dy = 0; dy < 3; ++dy) {
            int srow = row + dy - 1;
            __syncthreads();          // rb region free (prev phase/iter done)
#pragma unroll
            for (int ii = 0; ii < 3; ++ii) {
                int unit = t + ii * 256;
                if (unit < 528) {
                    int pxi = unit >> 3; int cg = unit & 7; int spx = pxi - 1;
                    uint4 v = {0u, 0u, 0u, 0u};
                    if (((unsigned)srow < 64u) && ((unsigned)spx < 64u))
                        v = *(const uint4*)(inT + (((size_t)srow * 64 + spx) << 6) + cg * 8);
                    *(uint4*)(rb + (cg * 66 + pxi) * 8) = v;
                }
            }
            __syncthreads();
#pragma unroll
            for (int s = 0; s < 6; ++s) {
                int dxk = s >> 1; int cgb = (s & 1) * 4 + q;
                bf16x8 af = *(const bf16x8*)(rb + (cgb * 66 + w * 16 + n + dxk) * 8);
                int kb = (br * 72 + dy * 24 + s * 4 + q) * 32;
#pragma unroll
                for (int ot = 0; ot < 2; ++ot) {
                    bf16x8 bfg = *(const bf16x8*)(owb + (size_t)(kb + ot * 16 + n) * 8);
                    acc2[ot] = __builtin_amdgcn_mfma_f32_16x16x32_bf16(af, bfg, acc2[ot], 0, 0, 0);
                }
            }
        }
        // D-frags (+bias) -> sOff[j][px]; j=ot*16+n, px=w*16+q*4+r
#pragma unroll
        for (int ot = 0; ot < 2; ++ot) {
            int j = ot * 16 + n;
            float bias = (j < 27) ? obp[j] : 0.f;
#pragma unroll
            for (int r = 0; r < 4; ++r)
                sOff[j * 66 + w * 16 + q * 4 + r] = acc2[ot][r] + bias;
        }
        __syncthreads();   // sOff visible; rb dead -> sA/sW writable

        // ---- Phase A: bilinear coords + (mask*inbound)-folded weights ----
        for (int i2 = t; i2 < 576; i2 += 256) {
            int px = i2 & 63; int k = i2 >> 6;
            float dy = sOff[(2 * k) * 66 + px];
            float dx = sOff[(2 * k + 1) * 66 + px];
            float mm = sOff[(18 + k) * 66 + px];
            float m = sigf(mm);
            int ki = k / 3, kj = k % 3;
            float py  = (float)(row + ki - 1) + dy;
            float pxx = (float)(px + kj - 1) + dx;
            float y0f = floorf(py), x0f = floorf(pxx);
            float wy = py - y0f, wx = pxx - x0f;
            int y0 = (int)y0f, x0 = (int)x0f;
            float y0i = ((unsigned)y0 < 64u) ? 1.f : 0.f;
            float y1i = ((unsigned)(y0 + 1) < 64u) ? 1.f : 0.f;
            float x0i = ((unsigned)x0 < 64u) ? 1.f : 0.f;
            float x1i = ((unsigned)(x0 + 1) < 64u) ? 1.f : 0.f;
            float w00 = (1.f - wy) * (1.f - wx) * m * y0i * x0i;
            float w01 = (1.f - wy) * wx         * m * y0i * x1i;
            float w10 = wy         * (1.f - wx) * m * y1i * x0i;
            float w11 = wy         * wx         * m * y1i * x1i;
            int cy0 = min(max(y0, 0), 63),     cy1 = min(max(y0 + 1, 0), 63);
            int cx0 = min(max(x0, 0), 63),     cx1 = min(max(x0 + 1, 0), 63);
            sA[k * 64 + px] = make_uint2((unsigned)(cy0 * 64 + cx0) | ((unsigned)(cy0 * 64 + cx1) << 16),
                                         (unsigned)(cy1 * 64 + cx0) | ((unsigned)(cy1 * 64 + cx1) << 16));
            sWp[k * 64 + px] = make_float4(w00, w01, w10, w11);
        }
        __syncthreads();

        // ---- gather directly into A-frags + main MFMA ----
        const unsigned short* cbase = inT + q * 8;
        for (int ktap = 0; ktap < 9; ++ktap) {
            uint2 aa = sA[ktap * 64 + pxl];
            float4 wv = sWp[ktap * 64 + pxl];
            unsigned i0 = (aa.x & 0xffffu) << 6;
            unsigned i1 = (aa.x >> 16) << 6;
            unsigned i2 = (aa.y & 0xffffu) << 6;
            unsigned i3 = (aa.y >> 16) << 6;
#pragma unroll
            for (int half = 0; half < 2; ++half) {
                int s = ktap * 2 + half;
                const unsigned short* cb = cbase + half * 32;
                // sequential corner accumulation: one uint4 live at a time
                float sacc[8];
                {
                    uint4 A = *(const uint4*)(cb + i0);
                    sacc[0] = wv.x * blo(A.x); sacc[1] = wv.x * bhi(A.x);
                    sacc[2] = wv.x * blo(A.y); sacc[3] = wv.x * bhi(A.y);
                    sacc[4] = wv.x * blo(A.z); sacc[5] = wv.x * bhi(A.z);
                    sacc[6] = wv.x * blo(A.w); sacc[7] = wv.x * bhi(A.w);
                }
                {
                    uint4 A = *(const uint4*)(cb + i1);
                    sacc[0] += wv.y * blo(A.x); sacc[1] += wv.y * bhi(A.x);
                    sacc[2] += wv.y * blo(A.y); sacc[3] += wv.y * bhi(A.y);
                    sacc[4] += wv.y * blo(A.z); sacc[5] += wv.y * bhi(A.z);
                    sacc[6] += wv.y * blo(A.w); sacc[7] += wv.y * bhi(A.w);
                }
                {
                    uint4 A = *(const uint4*)(cb + i2);
                    sacc[0] += wv.z * blo(A.x); sacc[1] += wv.z * bhi(A.x);
                    sacc[2] += wv.z * blo(A.y); sacc[3] += wv.z * bhi(A.y);
                    sacc[4] += wv.z * blo(A.z); sacc[5] += wv.z * bhi(A.z);
                    sacc[6] += wv.z * blo(A.w); sacc[7] += wv.z * bhi(A.w);
                }
                {
                    uint4 A = *(const uint4*)(cb + i3);
                    sacc[0] += wv.w * blo(A.x); sacc[1] += wv.w * bhi(A.x);
                    sacc[2] += wv.w * blo(A.y); sacc[3] += wv.w * bhi(A.y);
                    sacc[4] += wv.w * blo(A.z); sacc[5] += wv.w * bhi(A.z);
                    sacc[6] += wv.w * blo(A.w); sacc[7] += wv.w * bhi(A.w);
                }
                bf16x8 af;
#pragma unroll
                for (int j = 0; j < 8; ++j) af[j] = (__bf16)sacc[j];
                int kb = (br * 72 + s * 4 + q) * 64;
#pragma unroll
                for (int ot = 0; ot < 4; ++ot) {
                    bf16x8 bfg = *(const bf16x8*)(wBp + (size_t)(kb + ot * 16 + n) * 8);
                    acc[ot] = __builtin_amdgcn_mfma_f32_16x16x32_bf16(af, bfg, acc[ot], 0, 0, 0);
                }
            }
        }
        __syncthreads();   // protect sA/sW/arena before next sub's rb staging
    }

    // epilogue: direct D-scrambled coalesced store; K3 decodes.
    float* gp = p.ws + WS_GATES + ((size_t)((gate * 8 + b) * 64 + row) << 12);
#pragma unroll
    for (int ot = 0; ot < 4; ++ot)
        *(float4*)(gp + ((w * 4 + ot) * 64 + l) * 4) = *(float4*)&acc[ot];
}

// ---------------------------------------------------------------------------
// K3: pointwise ConvLSTM combine, reading D-scrambled gates (coalesced) and
//   decoding (o,px) for c/out access (16B-segment granularity).
//   grid: 8192 blocks of 256.
// ---------------------------------------------------------------------------
__global__ __launch_bounds__(256) void k3_lstm(Params p) {
    int T = blockIdx.x * 256 + threadIdx.x;        // [b][row][i] over scrambled
    int i = T & 4095; int row = (T >> 12) & 63; int b = T >> 18;
    const float* gp = p.ws + WS_GATES;
    size_t base = ((size_t)(b * 64 + row) << 12) + i;
    float gi = gp[base];
    float gf = gp[base + 1 * PLANE];
    float gc = gp[base + 2 * PLANE];
    float go = gp[base + 3 * PLANE];
    // decode scramble: i = ((w*4+ot)*64 + l)*4 + r
    int r = i & 3; int l = (i >> 2) & 63; int u = i >> 8;
    int w = u >> 2; int ot = u & 3;
    int o = ot * 16 + (l & 15);
    int px = w * 16 + (l >> 4) * 4 + r;
    size_t cidx = ((size_t)(b * 64 + o) << 12) + row * 64 + px;
    float cold = p.c[cidx];
    float ig = sigf(gi + cold * p.wci[o] + p.bi[o]);
    float fg = sigf(gf + cold * p.wcf[o] + p.bf[o]);
    float cn = fg * cold + ig * tanhf(gc + p.bc[o]);
    float og = sigf(go + cn * p.wco[o] + p.bo[o]);
    p.out[cidx] = og * tanhf(cn);
    p.out[cidx + PLANE] = cn;
}

// ---------------------------------------------------------------------------
extern "C" void kernel_launch(void* const* d_in, const int* in_sizes, int n_in,
                              void* d_out, int out_size, void* d_ws, size_t ws_size,
                              hipStream_t stream) {
    (void)in_sizes; (void)n_in; (void)out_size; (void)ws_size;
    Params P;
    P.x = (const float*)d_in[0];
    P.h = (const float*)d_in[1];
    P.c = (const float*)d_in[2];
    for (int i = 0; i < 8; ++i) {
        P.w[i]  = (const float*)d_in[3 + 3 * i];
        P.ow[i] = (const float*)d_in[4 + 3 * i];
        P.ob[i] = (const float*)d_in[5 + 3 * i];
    }
    P.bi  = (const float*)d_in[27];
    P.bf  = (const float*)d_in[28];
    P.bc  = (const float*)d_in[29];
    P.bo  = (const float*)d_in[30];
    P.wci = (const float*)d_in[31];
    P.wcf = (const float*)d_in[32];
    P.wco = (const float*)d_in[33];
    P.out = (float*)d_out;
    P.ws  = (float*)d_ws;

    k0_prep   <<<dim3(1729), dim3(256), 0, stream>>>(P);
    k0_transp <<<dim3(1024), dim3(256), 0, stream>>>(P);
    k2_fused  <<<dim3(2048), dim3(256), 0, stream>>>(P);
    k3_lstm   <<<dim3(8192), dim3(256), 0, stream>>>(P);
}

// Round 9
// 336.025 us; speedup vs baseline: 1.8686x; 1.0657x over previous
//
#include <hip/hip_runtime.h>
#include <math.h>

// Problem constants (B=8, Cin=Cout=64, H=W=64, 3x3 kernel pad 1)
#define NB     8
#define NC     64
#define HW     4096           // 64*64
#define PLANE  2097152        // NB*NC*HW

// Workspace layout (float-slot offsets)
#define WS_WB     0           // bf16 wB[8][72][64][8]   (294912 bf16 = 147456 f)
#define WS_OWB    147456      // bf16 owB[8][72][32][8]  (147456 bf16 = 73728 f)
#define WS_OB     221184      // f32 obAll[8][27]
#define WS_GATES  221400      // f32 gates_scr[4][8][64][4096] = 8388608 (D-scrambled)
#define WS_XT     8610008     // bf16 xT[8][4096][64] HWC  (1048576 f)
#define WS_HT     9658584     // bf16 hT[8][4096][64] HWC  (1048576 f)
// total = 10707160 floats = 42.8 MB

typedef __bf16 bf16x8 __attribute__((ext_vector_type(8)));
typedef float  f32x4  __attribute__((ext_vector_type(4)));

struct Params {
    const float* x; const float* h; const float* c;
    const float* w[8]; const float* ow[8]; const float* ob[8];
    const float* bi; const float* bf; const float* bc; const float* bo;
    const float* wci; const float* wcf; const float* wco;
    float* out; float* ws;
};

__device__ __forceinline__ float sigf(float v) { return 1.f / (1.f + __expf(-v)); }
__device__ __forceinline__ float tanhfast(float v) {
    return 1.f - 2.f / (__expf(2.f * v) + 1.f);
}
__device__ __forceinline__ unsigned short f2bf(float v) {
    __bf16 b = (__bf16)v;
    return __builtin_bit_cast(unsigned short, b);
}
// bf16 pair unpack: lo/hi halves of a dword -> f32 (1 inst each)
__device__ __forceinline__ float blo(unsigned d) { return __builtin_bit_cast(float, d << 16); }
__device__ __forceinline__ float bhi(unsigned d) { return __builtin_bit_cast(float, d & 0xffff0000u); }

// ---------------------------------------------------------------------------
// K0 (merged): weight B-frag packing + biases (blocks 0..1728), and
//   CHW fp32 -> HWC bf16 transpose of x/h (blocks 1729..2752).
// ---------------------------------------------------------------------------
__global__ __launch_bounds__(256) void k0_prep(Params p) {
    if (blockIdx.x < 1729) {
        int i = blockIdx.x * 256 + threadIdx.x;
        unsigned short* wb  = (unsigned short*)(p.ws + WS_WB);
        unsigned short* owb = (unsigned short*)(p.ws + WS_OWB);
        if (i < 294912) {
            int br = i / 36864; int r = i % 36864;
            int kgrp = r >> 9; int o = (r >> 3) & 63; int j = r & 7;
            int k = kgrp * 8 + j;
            int ktap = k >> 6; int c = k & 63;
            wb[i] = f2bf(p.w[br][(o * 64 + c) * 9 + ktap]);
        } else if (i < 294912 + 147456) {
            int ii = i - 294912;
            int br = ii / 18432; int r = ii % 18432;
            int kgrp = r >> 8; int o = (r >> 3) & 31; int j = r & 7;
            int k = kgrp * 8 + j;
            int ktap = k >> 6; int c = k & 63;
            float v = (o < 27) ? p.ow[br][(o * 64 + c) * 9 + ktap] : 0.f;
            owb[ii] = f2bf(v);
        } else if (i < 294912 + 147456 + 216) {
            int ii = i - 442368;
            int br = ii / 27; int j = ii % 27;
            p.ws[WS_OB + ii] = p.ob[br][j];
        }
        return;
    }
    __shared__ float tile[64][65];
    int bid = blockIdx.x - 1729;
    int row = bid & 63; int b = (bid >> 6) & 7; int ten = bid >> 9;
    const float* src = ten ? p.h : p.x;
    unsigned short* dst = (unsigned short*)(p.ws + (ten ? WS_HT : WS_XT));
    int t = threadIdx.x; int lane = t & 63; int w4 = t >> 6;
#pragma unroll
    for (int i = 0; i < 16; ++i) {
        int c = i * 4 + w4;
        tile[c][lane] = src[((size_t)(b * 64 + c) << 12) + row * 64 + lane];
    }
    __syncthreads();
#pragma unroll
    for (int i = 0; i < 16; ++i) {
        int px = i * 4 + w4;
        dst[((size_t)(b * 4096 + row * 64 + px) << 6) + lane] = f2bf(tile[lane][px]);
    }
}

// ---------------------------------------------------------------------------
// K2 v9 (fused, software-pipelined gather): offset-conv + deform + MFMA.
//   grid: gate(4) * row(64) * b(8) = 2048 blocks of 256. Wave = px-tile.
//   Gather loop pipelined at half-step granularity: tap k's 8 corner loads
//   (both 32-ch halves) issued before processing; tap k+1's half-0 loads
//   issued before half-1 is processed. #pragma unroll 1 pins the shape
//   (full unroll caused the R6 hoist-spill). __launch_bounds__(256,3).
//   LDS arena 22272 B: rb(8448) aliases sA(4608)+sW(9216); sOff(8448) after.
// ---------------------------------------------------------------------------
__global__ __launch_bounds__(256, 3) void k2_fused(Params p) {
    __shared__ __align__(16) unsigned char arena[22272];
    unsigned short* rb = (unsigned short*)arena;            // [cg][px+2][8] bf16
    uint2*  sA   = (uint2*)arena;                           // [9][64]
    float4* sWp  = (float4*)(arena + 4608);                 // [9][64]
    float*  sOff = (float*)(arena + 13824);                 // [32][66]

    int bid = blockIdx.x;
    int gate = bid & 3; int row = (bid >> 2) & 63; int b = bid >> 8;
    int t = threadIdx.x; int l = t & 63; int w = t >> 6;
    int q = l >> 4; int n = l & 15;
    int pxl = w * 16 + n;

    const unsigned short* wBp = (const unsigned short*)(p.ws + WS_WB);
    const unsigned short* owb = (const unsigned short*)(p.ws + WS_OWB);

    f32x4 acc[4];
#pragma unroll
    for (int ot = 0; ot < 4; ++ot) acc[ot] = (f32x4){0.f, 0.f, 0.f, 0.f};

    for (int sub = 0; sub < 2; ++sub) {
        int br = gate * 2 + sub;
        const unsigned short* inT =
            (const unsigned short*)(p.ws + (sub ? WS_HT : WS_XT)) + ((size_t)b << 18);
        const float* obp = p.ws + WS_OB + br * 27;

        // ---- fused offset conv: M=16 px (this wave's tile), N=32, K=576 ----
        f32x4 acc2[2];
        acc2[0] = (f32x4){0.f, 0.f, 0.f, 0.f};
        acc2[1] = (f32x4){0.f, 0.f, 0.f, 0.f};
        for (int dy = 0; dy < 3; ++dy) {
            int srow = row + dy - 1;
            __syncthreads();          // rb region free (prev phase/iter done)
#pragma unroll
            for (int ii = 0; ii < 3; ++ii) {
                int unit = t + ii * 256;
                if (unit < 528) {
                    int pxi = unit >> 3; int cg = unit & 7; int spx = pxi - 1;
                    uint4 v = {0u, 0u, 0u, 0u};
                    if (((unsigned)srow < 64u) && ((unsigned)spx < 64u))
                        v = *(const uint4*)(inT + (((size_t)srow * 64 + spx) << 6) + cg * 8);
                    *(uint4*)(rb + (cg * 66 + pxi) * 8) = v;
                }
            }
            __syncthreads();
#pragma unroll
            for (int s = 0; s < 6; ++s) {
                int dxk = s >> 1; int cgb = (s & 1) * 4 + q;
                bf16x8 af = *(const bf16x8*)(rb + (cgb * 66 + w * 16 + n + dxk) * 8);
                int kb = (br * 72 + dy * 24 + s * 4 + q) * 32;
#pragma unroll
                for (int ot = 0; ot < 2; ++ot) {
                    bf16x8 bfg = *(const bf16x8*)(owb + (size_t)(kb + ot * 16 + n) * 8);
                    acc2[ot] = __builtin_amdgcn_mfma_f32_16x16x32_bf16(af, bfg, acc2[ot], 0, 0, 0);
                }
            }
        }
        // D-frags (+bias) -> sOff[j][px]; j=ot*16+n, px=w*16+q*4+r
#pragma unroll
        for (int ot = 0; ot < 2; ++ot) {
            int j = ot * 16 + n;
            float bias = (j < 27) ? obp[j] : 0.f;
#pragma unroll
            for (int r = 0; r < 4; ++r)
                sOff[j * 66 + w * 16 + q * 4 + r] = acc2[ot][r] + bias;
        }
        __syncthreads();   // sOff visible; rb dead -> sA/sW writable

        // ---- Phase A: bilinear coords + (mask*inbound)-folded weights ----
        for (int i2 = t; i2 < 576; i2 += 256) {
            int px = i2 & 63; int k = i2 >> 6;
            float dy = sOff[(2 * k) * 66 + px];
            float dx = sOff[(2 * k + 1) * 66 + px];
            float mm = sOff[(18 + k) * 66 + px];
            float m = sigf(mm);
            int ki = k / 3, kj = k % 3;
            float py  = (float)(row + ki - 1) + dy;
            float pxx = (float)(px + kj - 1) + dx;
            float y0f = floorf(py), x0f = floorf(pxx);
            float wy = py - y0f, wx = pxx - x0f;
            int y0 = (int)y0f, x0 = (int)x0f;
            float y0i = ((unsigned)y0 < 64u) ? 1.f : 0.f;
            float y1i = ((unsigned)(y0 + 1) < 64u) ? 1.f : 0.f;
            float x0i = ((unsigned)x0 < 64u) ? 1.f : 0.f;
            float x1i = ((unsigned)(x0 + 1) < 64u) ? 1.f : 0.f;
            float w00 = (1.f - wy) * (1.f - wx) * m * y0i * x0i;
            float w01 = (1.f - wy) * wx         * m * y0i * x1i;
            float w10 = wy         * (1.f - wx) * m * y1i * x0i;
            float w11 = wy         * wx         * m * y1i * x1i;
            int cy0 = min(max(y0, 0), 63),     cy1 = min(max(y0 + 1, 0), 63);
            int cx0 = min(max(x0, 0), 63),     cx1 = min(max(x0 + 1, 0), 63);
            sA[k * 64 + px] = make_uint2((unsigned)(cy0 * 64 + cx0) | ((unsigned)(cy0 * 64 + cx1) << 16),
                                         (unsigned)(cy1 * 64 + cx0) | ((unsigned)(cy1 * 64 + cx1) << 16));
            sWp[k * 64 + px] = make_float4(w00, w01, w10, w11);
        }
        __syncthreads();

        // ---- pipelined gather into A-frags + main MFMA ----
        const unsigned short* cbase = inT + q * 8;

#define PROC(Ca, Cb, Cc, Cd, WV, S)                                            \
        {                                                                      \
            float sacc[8];                                                     \
            sacc[0] = WV.x * blo(Ca.x); sacc[1] = WV.x * bhi(Ca.x);            \
            sacc[2] = WV.x * blo(Ca.y); sacc[3] = WV.x * bhi(Ca.y);            \
            sacc[4] = WV.x * blo(Ca.z); sacc[5] = WV.x * bhi(Ca.z);            \
            sacc[6] = WV.x * blo(Ca.w); sacc[7] = WV.x * bhi(Ca.w);            \
            sacc[0] += WV.y * blo(Cb.x); sacc[1] += WV.y * bhi(Cb.x);          \
            sacc[2] += WV.y * blo(Cb.y); sacc[3] += WV.y * bhi(Cb.y);          \
            sacc[4] += WV.y * blo(Cb.z); sacc[5] += WV.y * bhi(Cb.z);          \
            sacc[6] += WV.y * blo(Cb.w); sacc[7] += WV.y * bhi(Cb.w);          \
            sacc[0] += WV.z * blo(Cc.x); sacc[1] += WV.z * bhi(Cc.x);          \
            sacc[2] += WV.z * blo(Cc.y); sacc[3] += WV.z * bhi(Cc.y);          \
            sacc[4] += WV.z * blo(Cc.z); sacc[5] += WV.z * bhi(Cc.z);          \
            sacc[6] += WV.z * blo(Cc.w); sacc[7] += WV.z * bhi(Cc.w);          \
            sacc[0] += WV.w * blo(Cd.x); sacc[1] += WV.w * bhi(Cd.x);          \
            sacc[2] += WV.w * blo(Cd.y); sacc[3] += WV.w * bhi(Cd.y);          \
            sacc[4] += WV.w * blo(Cd.z); sacc[5] += WV.w * bhi(Cd.z);          \
            sacc[6] += WV.w * blo(Cd.w); sacc[7] += WV.w * bhi(Cd.w);          \
            bf16x8 af;                                                         \
            _Pragma("unroll")                                                  \
            for (int j = 0; j < 8; ++j) af[j] = (__bf16)sacc[j];               \
            int kb = (br * 72 + (S) * 4 + q) * 64;                             \
            _Pragma("unroll")                                                  \
            for (int ot = 0; ot < 4; ++ot) {                                   \
                bf16x8 bfg = *(const bf16x8*)(wBp + (size_t)(kb + ot * 16 + n) * 8); \
                acc[ot] = __builtin_amdgcn_mfma_f32_16x16x32_bf16(af, bfg, acc[ot], 0, 0, 0); \
            }                                                                  \
        }

        // prologue: tap 0 addresses + half-0 loads
        uint2 aa = sA[pxl];
        float4 wv = sWp[pxl];
        unsigned i0 = (aa.x & 0xffffu) << 6, i1 = (aa.x >> 16) << 6;
        unsigned i2 = (aa.y & 0xffffu) << 6, i3 = (aa.y >> 16) << 6;
        uint4 C0a = *(const uint4*)(cbase + i0);
        uint4 C0b = *(const uint4*)(cbase + i1);
        uint4 C0c = *(const uint4*)(cbase + i2);
        uint4 C0d = *(const uint4*)(cbase + i3);
#pragma unroll 1
        for (int ktap = 0; ktap < 9; ++ktap) {
            // issue current tap's half-1 loads (same corners, +32 ch)
            uint4 C1a = *(const uint4*)(cbase + 32 + i0);
            uint4 C1b = *(const uint4*)(cbase + 32 + i1);
            uint4 C1c = *(const uint4*)(cbase + 32 + i2);
            uint4 C1d = *(const uint4*)(cbase + 32 + i3);
            // process half-0
            PROC(C0a, C0b, C0c, C0d, wv, ktap * 2)
            // prefetch next tap's addresses + half-0 loads
            float4 wvn = wv;
            if (ktap < 8) {
                uint2 aan = sA[(ktap + 1) * 64 + pxl];
                wvn = sWp[(ktap + 1) * 64 + pxl];
                i0 = (aan.x & 0xffffu) << 6; i1 = (aan.x >> 16) << 6;
                i2 = (aan.y & 0xffffu) << 6; i3 = (aan.y >> 16) << 6;
                C0a = *(const uint4*)(cbase + i0);
                C0b = *(const uint4*)(cbase + i1);
                C0c = *(const uint4*)(cbase + i2);
                C0d = *(const uint4*)(cbase + i3);
            }
            // process half-1
            PROC(C1a, C1b, C1c, C1d, wv, ktap * 2 + 1)
            wv = wvn;
        }
#undef PROC
        __syncthreads();   // protect sA/sW/arena before next sub's rb staging
    }

    // epilogue: direct D-scrambled coalesced store; K3 decodes.
    float* gp = p.ws + WS_GATES + ((size_t)((gate * 8 + b) * 64 + row) << 12);
#pragma unroll
    for (int ot = 0; ot < 4; ++ot)
        *(float4*)(gp + ((w * 4 + ot) * 64 + l) * 4) = *(float4*)&acc[ot];
}

// ---------------------------------------------------------------------------
// K3: pointwise ConvLSTM combine, reading D-scrambled gates (coalesced) and
//   decoding (o,px) for c/out access (16B-segment granularity).
//   grid: 8192 blocks of 256.
// ---------------------------------------------------------------------------
__global__ __launch_bounds__(256) void k3_lstm(Params p) {
    int T = blockIdx.x * 256 + threadIdx.x;        // [b][row][i] over scrambled
    int i = T & 4095; int row = (T >> 12) & 63; int b = T >> 18;
    const float* gp = p.ws + WS_GATES;
    size_t base = ((size_t)(b * 64 + row) << 12) + i;
    float gi = gp[base];
    float gf = gp[base + 1 * PLANE];
    float gc = gp[base + 2 * PLANE];
    float go = gp[base + 3 * PLANE];
    // decode scramble: i = ((w*4+ot)*64 + l)*4 + r
    int r = i & 3; int l = (i >> 2) & 63; int u = i >> 8;
    int w = u >> 2; int ot = u & 3;
    int o = ot * 16 + (l & 15);
    int px = w * 16 + (l >> 4) * 4 + r;
    size_t cidx = ((size_t)(b * 64 + o) << 12) + row * 64 + px;
    float cold = p.c[cidx];
    float ig = sigf(gi + cold * p.wci[o] + p.bi[o]);
    float fg = sigf(gf + cold * p.wcf[o] + p.bf[o]);
    float cn = fg * cold + ig * tanhfast(gc + p.bc[o]);
    float og = sigf(go + cn * p.wco[o] + p.bo[o]);
    p.out[cidx] = og * tanhfast(cn);
    p.out[cidx + PLANE] = cn;
}

// ---------------------------------------------------------------------------
extern "C" void kernel_launch(void* const* d_in, const int* in_sizes, int n_in,
                              void* d_out, int out_size, void* d_ws, size_t ws_size,
                              hipStream_t stream) {
    (void)in_sizes; (void)n_in; (void)out_size; (void)ws_size;
    Params P;
    P.x = (const float*)d_in[0];
    P.h = (const float*)d_in[1];
    P.c = (const float*)d_in[2];
    for (int i = 0; i < 8; ++i) {
        P.w[i]  = (const float*)d_in[3 + 3 * i];
        P.ow[i] = (const float*)d_in[4 + 3 * i];
        P.ob[i] = (const float*)d_in[5 + 3 * i];
    }
    P.bi  = (const float*)d_in[27];
    P.bf  = (const float*)d_in[28];
    P.bc  = (const float*)d_in[29];
    P.bo  = (const float*)d_in[30];
    P.wci = (const float*)d_in[31];
    P.wcf = (const float*)d_in[32];
    P.wco = (const float*)d_in[33];
    P.out = (float*)d_out;
    P.ws  = (float*)d_ws;

    k0_prep   <<<dim3(2753), dim3(256), 0, stream>>>(P);
    k2_fused  <<<dim3(2048), dim3(256), 0, stream>>>(P);
    k3_lstm   <<<dim3(8192), dim3(256), 0, stream>>>(P);
}